// Round 1
// baseline (270.863 us; speedup 1.0000x reference)
//
#include <hip/hip_runtime.h>
#include <hip/hip_bf16.h>
#include <hip/hip_fp16.h>
#include <stdint.h>
#include <stddef.h>
#include <string.h>

#define D_EMB 1024
#define SEQ   2048
#define BATCH 4

typedef short bf16x8  __attribute__((ext_vector_type(8)));
typedef short short8  __attribute__((ext_vector_type(8)));
typedef float f32x4   __attribute__((ext_vector_type(4)));

#define AS1 __attribute__((address_space(1)))
#define AS3 __attribute__((address_space(3)))

static __device__ __forceinline__ void async_copy16(const void* g, void* l) {
  __builtin_amdgcn_global_load_lds((const AS1 void*)g, (AS3 void*)l, 16, 0, 0);
}

// ============================================================================
// gemm256: C[256x256] tile = A[256xK] (row-major, lda) * Bt[256xK]^T.
// 8-phase schedule (T3+T4+T5 on top of the verified chunk-XOR swizzle = T2).
//  - 512 threads = 8 waves in 2(M)x4(N); per-wave output 128x64 = acc[8][4].
//  - BK=64; LDS = 2 buffers x (A 256x64 + B 256x64) bf16 = 128 KiB.
//  - LDS swizzle: physical 16B chunk  c ^ (row & 7)  (0 bank conflicts,
//    verified on the previous 128^2 kernel). global_load_lds dest is linear;
//    the *source* column is pre-swizzled (both-sides-or-neither rule).
//  - Per phase: {ds-load quadrant frags | stage ONE half-tile (2x
//    global_load_lds dwordx4) | raw s_barrier | setprio(1) 16xMFMA setprio(0)
//    | raw s_barrier}.  NO __syncthreads() anywhere in the loop: its implicit
//    s_waitcnt vmcnt(0) drain is the old ~660TF ceiling.
//  - Counted vmcnt(4) ONLY at phases 4 and 8. Staging ledger (sound, each
//    half-slot overwritten >=1 closing-barrier after its last ds_read):
//      p1: B-lo(t+1)   p2: A-hi(t+1)   p3: A-lo(t+2)   p4: B-hi(t+2) +vmcnt4
//      p5: B-lo(t+2)   p6: A-hi(t+2)   p7: A-lo(t+3)   p8: B-hi(t+3) +vmcnt4
//    Quadrant order p1:(h0,g0) p2:(h0,g1) p3:(h1,g1) p4:(h1,g0); A-half read
//    once (p1/p3), so its slot frees 2 phases before the t+2 stage lands.
//    vmcnt(4) leaves exactly the 2 newest (not-yet-needed) halves in flight.
// ============================================================================

#define BAR     __builtin_amdgcn_s_barrier()
#define VMCNT4  asm volatile("s_waitcnt vmcnt(4)" ::: "memory")
#define VMCNT0  asm volatile("s_waitcnt vmcnt(0)" ::: "memory")

// stage one half-tile (128 rows x 64 cols): rows h*128 + [0,128), k-tile kt.
// thread t covers row (t>>3)+64*round, 16B chunk (t&7); source col swizzled.
#define STAGE_A(buf, h, kt) do {                                              \
    const __hip_bfloat16* _g = gA + (size_t)((h) * 128) * lda + ((kt) << 6);  \
    char* _l = (char*)sA + (buf) * 32768 + (h) * 16384 + wave * 1024;         \
    async_copy16(_g, _l);                                                     \
    async_copy16(_g + (size_t)64 * lda, _l + 8192);                           \
  } while (0)
#define STAGE_B(buf, h, kt) do {                                              \
    const __hip_bfloat16* _g = gB + (size_t)((h) * 128) * ldb + ((kt) << 6);  \
    char* _l = (char*)sB + (buf) * 32768 + (h) * 16384 + wave * 1024;         \
    async_copy16(_g, _l);                                                     \
    async_copy16(_g + (size_t)64 * ldb, _l + 8192);                           \
  } while (0)

// quadrant fragment loads (row&7 == lr&7 for all frag rows -> pc0/pc1 fixed)
#define LOAD_A(aF, lbuf, h) do {                                              \
    const __hip_bfloat16* _b = (lbuf) + (wr * 128 + (h) * 64 + lr) * 64;      \
    _Pragma("unroll")                                                         \
    for (int _i = 0; _i < 4; _i++) {                                          \
      aF[_i][0] = *(const bf16x8*)&_b[_i * 1024 + pc0];                       \
      aF[_i][1] = *(const bf16x8*)&_b[_i * 1024 + pc1];                       \
    }                                                                         \
  } while (0)
#define LOAD_B(bF, lbuf, g) do {                                              \
    const __hip_bfloat16* _b = (lbuf) + (wc * 64 + (g) * 32 + lr) * 64;       \
    _Pragma("unroll")                                                         \
    for (int _j = 0; _j < 2; _j++) {                                          \
      bF[_j][0] = *(const bf16x8*)&_b[_j * 1024 + pc0];                       \
      bF[_j][1] = *(const bf16x8*)&_b[_j * 1024 + pc1];                       \
    }                                                                         \
  } while (0)

#define MFMA_Q(aF, bF, h, g) do {                                             \
    __builtin_amdgcn_s_setprio(1);                                            \
    _Pragma("unroll")                                                         \
    for (int _i = 0; _i < 4; _i++)                                            \
      _Pragma("unroll")                                                       \
      for (int _j = 0; _j < 2; _j++) {                                        \
        acc[(h) * 4 + _i][(g) * 2 + _j] =                                     \
          __builtin_amdgcn_mfma_f32_16x16x32_bf16(aF[_i][0], bF[_j][0],       \
              acc[(h) * 4 + _i][(g) * 2 + _j], 0, 0, 0);                      \
        acc[(h) * 4 + _i][(g) * 2 + _j] =                                     \
          __builtin_amdgcn_mfma_f32_16x16x32_bf16(aF[_i][1], bF[_j][1],       \
              acc[(h) * 4 + _i][(g) * 2 + _j], 0, 0, 0);                      \
      }                                                                       \
    __builtin_amdgcn_s_setprio(0);                                            \
  } while (0)

static __device__ __forceinline__ void gemm256(
    const __hip_bfloat16* __restrict__ A, int lda,
    const __hip_bfloat16* __restrict__ Bt, int ldb,
    int K, f32x4 (&acc)[8][4])
{
  __shared__ __hip_bfloat16 sA[2][128 * 64 * 2];   // 64 KiB
  __shared__ __hip_bfloat16 sB[2][128 * 64 * 2];   // 64 KiB

  const int t    = threadIdx.x;   // 0..511
  const int wave = t >> 6;        // 0..7
  const int lane = t & 63;
  const int quad = lane >> 4;
  const int lr   = lane & 15;
  const int wr   = wave >> 2;     // 0..1  (M)
  const int wc   = wave & 3;      // 0..3  (N)

  // staging source (per-thread); swizzle key (r&7) identical for both rounds
  const int r0 = t >> 3;                         // 0..63
  const int cs = (((t & 7) ^ (r0 & 7)) << 3);    // swizzled source column
  const __hip_bfloat16* gA = A  + (size_t)r0 * lda + cs;
  const __hip_bfloat16* gB = Bt + (size_t)r0 * ldb + cs;

  // LDS read chunk offsets (elems): logical chunk quad (kk=0) / quad+4 (kk=32)
  const int pc0 = ((quad)     ^ (lr & 7)) << 3;
  const int pc1 = ((quad + 4) ^ (lr & 7)) << 3;

  const __hip_bfloat16* const lA0 = sA[0];
  const __hip_bfloat16* const lA1 = sA[1];
  const __hip_bfloat16* const lB0 = sB[0];
  const __hip_bfloat16* const lB1 = sB[1];

  const int nt    = K >> 6;   // K-tiles (>=4, even: 16 or 32 here)
  const int niter = nt >> 1;

  // prologue: tile0 complete + A-lo(1), B-hi(1); vmcnt(4) completes tile0.
  STAGE_A(0, 0, 0);
  STAGE_A(0, 1, 0);
  STAGE_B(0, 0, 0);
  STAGE_B(0, 1, 0);
  STAGE_A(1, 0, 1);
  STAGE_B(1, 1, 1);
  VMCNT4;
  BAR;

  bf16x8 aF[4][2], bFa[2][2], bFb[2][2];

  for (int j = 0; j < niter - 1; ++j) {
    const int tb = 2 * j + 1, tc = tb + 1, td = tb + 2;

    // ---------------- tile 2j (buf 0) ----------------
    LOAD_A(aF, lA0, 0); LOAD_B(bFa, lB0, 0);       // p1 (h0,g0)
    STAGE_B(1, 0, tb);
    BAR; MFMA_Q(aF, bFa, 0, 0); BAR;

    LOAD_B(bFb, lB0, 1);                            // p2 (h0,g1)
    STAGE_A(1, 1, tb);
    BAR; MFMA_Q(aF, bFb, 0, 1); BAR;

    LOAD_A(aF, lA0, 1);                             // p3 (h1,g1)
    STAGE_A(0, 0, tc);
    BAR; MFMA_Q(aF, bFb, 1, 1); BAR;

    STAGE_B(0, 1, tc);                              // p4 (h1,g0)
    VMCNT4;                                         // tile tb complete
    BAR; MFMA_Q(aF, bFa, 1, 0); BAR;

    // ---------------- tile 2j+1 (buf 1) ----------------
    LOAD_A(aF, lA1, 0); LOAD_B(bFa, lB1, 0);       // p5 (h0,g0)
    STAGE_B(0, 0, tc);
    BAR; MFMA_Q(aF, bFa, 0, 0); BAR;

    LOAD_B(bFb, lB1, 1);                            // p6 (h0,g1)
    STAGE_A(0, 1, tc);
    BAR; MFMA_Q(aF, bFb, 0, 1); BAR;

    LOAD_A(aF, lA1, 1);                             // p7 (h1,g1)
    STAGE_A(1, 0, td);
    BAR; MFMA_Q(aF, bFb, 1, 1); BAR;

    STAGE_B(1, 1, td);                              // p8 (h1,g0)
    VMCNT4;                                         // tile tc complete
    BAR; MFMA_Q(aF, bFa, 1, 0); BAR;
  }

  // ---------------- final iter: tiles nt-2 (buf0), nt-1 (buf1) ----------------
  {
    const int tb = nt - 1;
    LOAD_A(aF, lA0, 0); LOAD_B(bFa, lB0, 0);
    STAGE_B(1, 0, tb);
    BAR; MFMA_Q(aF, bFa, 0, 0); BAR;

    LOAD_B(bFb, lB0, 1);
    STAGE_A(1, 1, tb);
    BAR; MFMA_Q(aF, bFb, 0, 1); BAR;

    LOAD_A(aF, lA0, 1);
    BAR; MFMA_Q(aF, bFb, 1, 1); BAR;

    VMCNT0;                                         // tile nt-1 complete
    BAR; MFMA_Q(aF, bFa, 1, 0); BAR;

    LOAD_A(aF, lA1, 0); LOAD_B(bFa, lB1, 0);
    BAR; MFMA_Q(aF, bFa, 0, 0); BAR;

    LOAD_B(bFb, lB1, 1);
    BAR; MFMA_Q(aF, bFb, 0, 1); BAR;

    LOAD_A(aF, lA1, 1);
    BAR; MFMA_Q(aF, bFb, 1, 1); BAR;

    MFMA_Q(aF, bFa, 1, 0);
  }
}

#define ZERO_ACC(acc)                         \
  {                                           \
    f32x4 _z = {0.f, 0.f, 0.f, 0.f};          \
    _Pragma("unroll")                         \
    for (int _i = 0; _i < 8; _i++)            \
      _Pragma("unroll")                       \
      for (int _j = 0; _j < 4; _j++)          \
        acc[_i][_j] = _z;                     \
  }

// ---------------- fused prep: z<3 -> transpose+cast W; z==3 -> cast x ----------------
__global__ __launch_bounds__(256) void prep_kernel(
    const float* __restrict__ x,
    const float* __restrict__ Wq,
    const float* __restrict__ Wk,
    const float* __restrict__ Wv,
    __hip_bfloat16* __restrict__ xb,
    __hip_bfloat16* __restrict__ Wt3)
{
  const int tx = threadIdx.x, ty = threadIdx.y;  // (32,8)
  if (blockIdx.z == 3) {
    const int tid = ty * 32 + tx;
    const size_t base = ((size_t)blockIdx.y * 32 + blockIdx.x) * 8192;
#pragma unroll
    for (int p = 0; p < 8; p++) {
      const size_t i = base + p * 1024 + tid * 4;
      const float4 v = *(const float4*)(x + i);
      __hip_bfloat16 o[4] = {__float2bfloat16(v.x), __float2bfloat16(v.y),
                             __float2bfloat16(v.z), __float2bfloat16(v.w)};
      *(uint64_t*)(xb + i) = *(uint64_t*)o;
    }
    return;
  }
  const float* src = (blockIdx.z == 0) ? Wq : (blockIdx.z == 1) ? Wk : Wv;
  __hip_bfloat16* dst = Wt3 + (size_t)blockIdx.z * D_EMB * D_EMB;
  __shared__ __hip_bfloat16 tile[32][33];
  const int x0 = blockIdx.x * 32;  // e
  const int y0 = blockIdx.y * 32;  // d
#pragma unroll
  for (int i = 0; i < 32; i += 8)
    tile[ty + i][tx] = __float2bfloat16(src[(size_t)(y0 + ty + i) * D_EMB + (x0 + tx)]);
  __syncthreads();
#pragma unroll
  for (int i = 0; i < 32; i += 8)
    dst[(size_t)(x0 + ty + i) * D_EMB + (y0 + tx)] = tile[tx][ty + i];
}

// ---------------- QKV projections (256^2 tiles, 8-phase) ----------------
// grid (32 m-tiles, 4 n-tiles, 3 mats), m fastest: consecutive blocks share
// the weight B-tile (2 MB/mat, L2-resident) and stream x through L3.
// z=0: Q[b][s][e], z=1: K[b][s][e], z=2: V transposed -> Vt[b][e][s]
__global__ __launch_bounds__(512, 2) void qkv_kernel(
    const __hip_bfloat16* __restrict__ xb,
    const __hip_bfloat16* __restrict__ Wt3,
    const float* __restrict__ bq,
    const float* __restrict__ bk,
    const float* __restrict__ bv,
    __hip_bfloat16* __restrict__ Q,
    __hip_bfloat16* __restrict__ Kb,
    __hip_bfloat16* __restrict__ Vt)
{
  const int mat = blockIdx.z;
  const int m0  = blockIdx.x * 256;   // row in [0, 8192)
  const int n0  = blockIdx.y * 256;   // output dim e

  f32x4 acc[8][4];
  ZERO_ACC(acc);

  gemm256(xb + (size_t)m0 * D_EMB, D_EMB,
          Wt3 + (size_t)mat * D_EMB * D_EMB + (size_t)n0 * D_EMB, D_EMB,
          D_EMB, acc);

  const float* bias = (mat == 0) ? bq : (mat == 1) ? bk : bv;

  const int t = threadIdx.x;
  const int wave = t >> 6, lane = t & 63;
  const int quad = lane >> 4, lr = lane & 15;
  const int wr = wave >> 2, wc = wave & 3;

#pragma unroll
  for (int i = 0; i < 8; i++) {
#pragma unroll
    for (int j = 0; j < 4; j++) {
      const int n = n0 + wc * 64 + j * 16 + lr;
      const float bb = bias[n];
      const int mbase = m0 + wr * 128 + i * 16 + quad * 4;
      if (mat == 2) {
        // Vt[b][n][s], s = mbase..mbase+3 contiguous -> one 8B store
        const int b = mbase >> 11, s = mbase & 2047;
        __hip_bfloat16 pk[4];
#pragma unroll
        for (int r = 0; r < 4; r++) pk[r] = __float2bfloat16(acc[i][j][r] + bb);
        *(uint64_t*)&Vt[(size_t)b * D_EMB * SEQ + (size_t)n * SEQ + s] = *(uint64_t*)pk;
      } else {
        __hip_bfloat16* dst = (mat == 0) ? Q : Kb;
#pragma unroll
        for (int r = 0; r < 4; r++)
          dst[(size_t)(mbase + r) * D_EMB + n] = __float2bfloat16(acc[i][j][r] + bb);
      }
    }
  }
}

// ---------------- scores = Q @ K^T * scale (fp16 out) ----------------
__global__ __launch_bounds__(512, 2) void scores_kernel(
    const __hip_bfloat16* __restrict__ Q,
    const __hip_bfloat16* __restrict__ Kb,
    __half* __restrict__ Sc)
{
  const int b  = blockIdx.z;
  const int m0 = blockIdx.y * 256;  // s_q
  const int n0 = blockIdx.x * 256;  // s_k

  f32x4 acc[8][4];
  ZERO_ACC(acc);

  gemm256(Q  + (size_t)b * SEQ * D_EMB + (size_t)m0 * D_EMB, D_EMB,
          Kb + (size_t)b * SEQ * D_EMB + (size_t)n0 * D_EMB, D_EMB,
          D_EMB, acc);

  __half* out = Sc + (size_t)b * SEQ * SEQ;
  const float scale = 0.03125f;  // 1/sqrt(1024)

  const int t = threadIdx.x;
  const int wave = t >> 6, lane = t & 63;
  const int quad = lane >> 4, lr = lane & 15;
  const int wr = wave >> 2, wc = wave & 3;

#pragma unroll
  for (int i = 0; i < 8; i++)
#pragma unroll
    for (int j = 0; j < 4; j++) {
      const int n = n0 + wc * 64 + j * 16 + lr;
#pragma unroll
      for (int r = 0; r < 4; r++) {
        const int m = m0 + wr * 128 + i * 16 + quad * 4 + r;
        out[(size_t)m * SEQ + n] = __float2half(acc[i][j][r] * scale);
      }
    }
}

// ---------------- row softmax: fp16 scores -> bf16 probs (16B vectorized) ----------------
__global__ __launch_bounds__(256) void softmax_kernel(
    const __half* __restrict__ Sc, __hip_bfloat16* __restrict__ P)
{
  const int row = blockIdx.x;  // 0..8191
  const __half* src = Sc + (size_t)row * SEQ;
  const int t = threadIdx.x;
  const int wave = t >> 6, lane = t & 63;

  const short8 raw = *(const short8*)(src + t * 8);
  float v[8];
#pragma unroll
  for (int i = 0; i < 8; i++) {
    const short si = raw[i];
    __half h;
    memcpy(&h, &si, sizeof(h));
    v[i] = __half2float(h);
  }

  float m = v[0];
#pragma unroll
  for (int i = 1; i < 8; i++) m = fmaxf(m, v[i]);
#pragma unroll
  for (int o = 32; o > 0; o >>= 1) m = fmaxf(m, __shfl_xor(m, o));

  __shared__ float redm[4];
  __shared__ float reds[4];
  if (lane == 0) redm[wave] = m;
  __syncthreads();
  m = fmaxf(fmaxf(redm[0], redm[1]), fmaxf(redm[2], redm[3]));

  float e[8], s = 0.f;
#pragma unroll
  for (int i = 0; i < 8; i++) { e[i] = __expf(v[i] - m); s += e[i]; }
#pragma unroll
  for (int o = 32; o > 0; o >>= 1) s += __shfl_xor(s, o);
  if (lane == 0) reds[wave] = s;
  __syncthreads();
  s = reds[0] + reds[1] + reds[2] + reds[3];

  const float inv = 1.f / s;
  short8 outp;
#pragma unroll
  for (int i = 0; i < 8; i++) {
    const __hip_bfloat16 b = __float2bfloat16(e[i] * inv);
    short sb;
    memcpy(&sb, &b, sizeof(sb));
    outp[i] = sb;
  }
  *(short8*)(P + (size_t)row * SEQ + t * 8) = outp;
}

// ---------------- out(fp32) = P @ V  (A = probs [sq][sk], Bt = Vt [e][sk]) ----------------
__global__ __launch_bounds__(512, 2) void pv_kernel(
    const __hip_bfloat16* __restrict__ P,
    const __hip_bfloat16* __restrict__ Vt,
    float* __restrict__ out)
{
  const int b  = blockIdx.z;
  const int m0 = blockIdx.y * 256;  // s_q
  const int n0 = blockIdx.x * 256;  // e

  f32x4 acc[8][4];
  ZERO_ACC(acc);

  gemm256(P  + (size_t)b * SEQ * SEQ   + (size_t)m0 * SEQ, SEQ,
          Vt + (size_t)b * D_EMB * SEQ + (size_t)n0 * SEQ, SEQ,
          SEQ, acc);

  float* o = out + (size_t)b * SEQ * D_EMB;

  const int t = threadIdx.x;
  const int wave = t >> 6, lane = t & 63;
  const int quad = lane >> 4, lr = lane & 15;
  const int wr = wave >> 2, wc = wave & 3;

#pragma unroll
  for (int i = 0; i < 8; i++)
#pragma unroll
    for (int j = 0; j < 4; j++) {
      const int n = n0 + wc * 64 + j * 16 + lr;
#pragma unroll
      for (int r = 0; r < 4; r++) {
        const int m = m0 + wr * 128 + i * 16 + quad * 4 + r;
        o[(size_t)m * D_EMB + n] = acc[i][j][r];
      }
    }
}

extern "C" void kernel_launch(void* const* d_in, const int* in_sizes, int n_in,
                              void* d_out, int out_size, void* d_ws, size_t ws_size,
                              hipStream_t stream) {
  const float* x  = (const float*)d_in[0];
  const float* Wq = (const float*)d_in[1];
  const float* bq = (const float*)d_in[2];
  const float* Wk = (const float*)d_in[3];
  const float* bk = (const float*)d_in[4];
  const float* Wv = (const float*)d_in[5];
  const float* bv = (const float*)d_in[6];
  float* out = (float*)d_out;

  char* ws = (char*)d_ws;
  __hip_bfloat16* xb  = (__hip_bfloat16*)(ws);
  __hip_bfloat16* Wt3 = (__hip_bfloat16*)(ws + 16777216);
  __hip_bfloat16* Q   = (__hip_bfloat16*)(ws + 23068672);
  __hip_bfloat16* Kb  = (__hip_bfloat16*)(ws + 39845888);
  __hip_bfloat16* Vt  = (__hip_bfloat16*)(ws + 56623104);
  __half*         Sc  = (__half*)        (ws + 73400320);   // 32 MB fp16
  __hip_bfloat16* P   = (__hip_bfloat16*)(ws + 140509184);
  // total = 140509184 + 33554432 = 174,063,616 bytes (~166 MB)

  prep_kernel  <<<dim3(32, 32, 4), dim3(32, 8), 0, stream>>>(x, Wq, Wk, Wv, xb, Wt3);
  qkv_kernel   <<<dim3(32, 4, 3),  512,        0, stream>>>(xb, Wt3, bq, bk, bv, Q, Kb, Vt);
  scores_kernel<<<dim3(8, 8, 4),   512,        0, stream>>>(Q, Kb, Sc);
  softmax_kernel<<<dim3(8192),     256,        0, stream>>>(Sc, P);
  pv_kernel    <<<dim3(4, 8, 4),   512,        0, stream>>>(P, Vt, out);
}